// Round 1
// baseline (141.247 us; speedup 1.0000x reference)
//
#include <hip/hip_runtime.h>

#define SIGMA_C 0.14f
#define L_CONST_C 0.0254f

// One fused element-wise kernel. Per-block MLP-constant folding into LDS,
// then float4-vectorized map over B elements.
__global__ __launch_bounds__(256) void ecoat_kernel(
    const float* __restrict__ res_in,   // d_in[2]  (B)
    const float* __restrict__ bc_in,    // d_in[3]  (B)
    const float* __restrict__ w_in,     // d_in[5]  (2)
    const float* __restrict__ VR_in,    // d_in[7]  (1)
    const float* __restrict__ logCv_in, // d_in[8]  (1)
    const float* __restrict__ jmin_in,  // d_in[9]  (1)
    const float* __restrict__ W0_in,    // d_in[10] (10)
    const float* __restrict__ b0_in,    // d_in[11] (10)
    const float* __restrict__ W1_in,    // d_in[12] (100) row-major (10,10)
    const float* __restrict__ b1_in,    // d_in[13] (10)
    const float* __restrict__ Wf_in,    // d_in[14] (10)
    const float* __restrict__ bf_in,    // d_in[15] (1)
    float* __restrict__ out,            // 4*B + 3 floats
    int n4, int B)
{
    __shared__ float sA[10], sW0[10], sB0[10], sMisc[4]; // sMisc: C, sw, jmin, VR

    const int tid = threadIdx.x;
    if (tid < 10) {
        // A[i] = sum_j Wf[j] * W1[j,i]   (fold lin1 + lin_final)
        float a = 0.f;
        #pragma unroll
        for (int j = 0; j < 10; ++j) a += Wf_in[j] * W1_in[j * 10 + tid];
        sA[tid]  = a;
        sW0[tid] = W0_in[tid];
        sB0[tid] = b0_in[tid];
    } else if (tid == 10) {
        float c = bf_in[0];
        #pragma unroll
        for (int j = 0; j < 10; ++j) c += Wf_in[j] * b1_in[j];
        sMisc[0] = c;                                   // C
        sMisc[1] = w_in[1] * powf(10.0f, -logCv_in[0]); // sw = w01 * 10^-logCv
        sMisc[2] = jmin_in[0];
        sMisc[3] = VR_in[0];
    }
    __syncthreads();

    // Hoist LDS constants into registers (static indices -> pure VGPR).
    float A[10], W0r[10], B0r[10];
    #pragma unroll
    for (int i = 0; i < 10; ++i) { A[i] = sA[i]; W0r[i] = sW0[i]; B0r[i] = sB0[i]; }
    const float C  = sMisc[0];
    const float sw = sMisc[1];
    const float jm = sMisc[2];
    const float vr = sMisc[3];

    float* __restrict__ thk_o = out;
    float* __restrict__ res_o = out + (size_t)B;
    float* __restrict__ bc_o  = out + 2 * (size_t)B;
    float* __restrict__ q_o   = out + 3 * (size_t)B;

    const int idx = blockIdx.x * blockDim.x + tid;
    if (idx < n4) {
        const float4 b4 = reinterpret_cast<const float4*>(bc_in)[idx];
        const float4 r4 = reinterpret_cast<const float4*>(res_in)[idx];
        float4 t4, rr4, q4;

        #pragma unroll
        for (int k = 0; k < 4; ++k) {
            const float bcv = (&b4.x)[k];
            const float rev = (&r4.x)[k];
            const float cur = SIGMA_C * bcv / (SIGMA_C * rev + L_CONST_C);
            float f = C;
            #pragma unroll
            for (int i = 0; i < 10; ++i)
                f += A[i] * fmaxf(cur * W0r[i] + B0r[i], 0.f);
            const float rho = 7.5e6f * __expf(-f) + 1e6f;
            const float t = sw * (cur - jm);
            (&t4.x)[k]  = t;
            (&rr4.x)[k] = t * rho;
            (&q4.x)[k]  = cur;
        }
        reinterpret_cast<float4*>(thk_o)[idx] = t4;
        reinterpret_cast<float4*>(res_o)[idx] = rr4;
        reinterpret_cast<float4*>(bc_o)[idx]  = make_float4(vr, vr, vr, vr);
        reinterpret_cast<float4*>(q_o)[idx]   = q4;
    }

    // Scalar tail (B not divisible by 4) — dead for B = 4M but kept for safety.
    const int tail_start = n4 * 4;
    const int tail_n = B - tail_start;
    if (blockIdx.x == 0 && tid < tail_n) {
        const int e = tail_start + tid;
        const float bcv = bc_in[e];
        const float rev = res_in[e];
        const float cur = SIGMA_C * bcv / (SIGMA_C * rev + L_CONST_C);
        float f = C;
        #pragma unroll
        for (int i = 0; i < 10; ++i)
            f += A[i] * fmaxf(cur * W0r[i] + B0r[i], 0.f);
        const float rho = 7.5e6f * __expf(-f) + 1e6f;
        const float t = sw * (cur - jm);
        thk_o[e] = t;
        res_o[e] = t * rho;
        bc_o[e]  = vr;
        q_o[e]   = cur;
    }

    // Trailing outputs: zeros_like(w) (2) + zeros_like(k) (1). d_out is poisoned.
    if (blockIdx.x == 0 && tid < 3) out[4 * (size_t)B + tid] = 0.f;
}

extern "C" void kernel_launch(void* const* d_in, const int* in_sizes, int n_in,
                              void* d_out, int out_size, void* d_ws, size_t ws_size,
                              hipStream_t stream) {
    // setup_inputs order:
    // 0:t 1:thk 2:res 3:bc_anode 4:Q 5:w 6:k 7:VR 8:logCv 9:jmin
    // 10:W0 11:b0 12:W1 13:b1 14:Wf 15:bf
    const float* res_in   = (const float*)d_in[2];
    const float* bc_in    = (const float*)d_in[3];
    const float* w_in     = (const float*)d_in[5];
    const float* VR_in    = (const float*)d_in[7];
    const float* logCv_in = (const float*)d_in[8];
    const float* jmin_in  = (const float*)d_in[9];
    const float* W0_in    = (const float*)d_in[10];
    const float* b0_in    = (const float*)d_in[11];
    const float* W1_in    = (const float*)d_in[12];
    const float* b1_in    = (const float*)d_in[13];
    const float* Wf_in    = (const float*)d_in[14];
    const float* bf_in    = (const float*)d_in[15];

    const int B  = in_sizes[3];   // 4,000,000
    const int n4 = B / 4;
    const int threads = 256;
    const int blocks = (n4 + threads - 1) / threads;

    ecoat_kernel<<<blocks, threads, 0, stream>>>(
        res_in, bc_in, w_in, VR_in, logCv_in, jmin_in,
        W0_in, b0_in, W1_in, b1_in, Wf_in, bf_in,
        (float*)d_out, n4, B);
}